// Round 12
// baseline (74.114 us; speedup 1.0000x reference)
//
#include <hip/hip_runtime.h>

// Problem constants (fixed by setup_inputs)
#define T_   16
#define TOK_ 16384
#define P_   8192
#define N_   32768
#define D_   128
#define L_   8
#define C_   16

typedef float f32x4 __attribute__((ext_vector_type(4)));

constexpr int K1_BLOCKS     = 1024;  // 4/CU
constexpr int BLOCKS_PER_T  = 64;    // K1 blocks per timestamp
constexpr int K3_BLOCKS     = 256;   // 1/CU; each block streams 1 MB (fill-like)

// ---------------------------------------------------------------------------
// Kernel 1: gather x rows at node_pos, LN(D=128) with algebraically-fused
// 8->1 pool, per-group-l accumulate -> partial[b][128].  (R11-proven)
// All 16 gather f32x4 loads + both passes' index loads issue up-front ->
// one memory round-trip per wave.
// ---------------------------------------------------------------------------
__global__ __launch_bounds__(256) void k1_gather_ln_pool(
    const float* __restrict__ x,
    const float* __restrict__ g_enc, const float* __restrict__ b_enc,
    const int* __restrict__ node_pos, const int* __restrict__ node_ids,
    float* __restrict__ partial)
{
    __shared__ float lds[4 * 128];
    const int tid   = threadIdx.x;
    const int lane  = tid & 63;
    const int wid   = tid >> 6;
    const int j     = lane & 15;   // channel sublane
    const int q     = lane >> 4;   // quarter (row within 4-row batch)
    const int b     = blockIdx.x;
    const int t     = b >> 6;      // 64 blocks per t
    const int chunk = b & 63;
    const int tP    = t * P_;
    const int pbase = chunk * 128 + wid * 16;   // pass 0 rows; pass 1 = +64
    const float* xt = x + (size_t)t * TOK_ * D_;

    const f32x4 g0  = *(const f32x4*)(g_enc + 8 * j);
    const f32x4 g1  = *(const f32x4*)(g_enc + 8 * j + 4);
    const f32x4 bb0 = *(const f32x4*)(b_enc + 8 * j);
    const f32x4 bb1 = *(const f32x4*)(b_enc + 8 * j + 4);
    const float G = g0.x + g0.y + g0.z + g0.w + g1.x + g1.y + g1.z + g1.w;
    const float B = bb0.x + bb0.y + bb0.z + bb0.w + bb1.x + bb1.y + bb1.z + bb1.w;

    int posv[2], nidv[2];
    posv[0] = node_pos[tP + pbase + j];
    nidv[0] = node_ids[tP + pbase + j];
    posv[1] = node_pos[tP + pbase + 64 + j];
    nidv[1] = node_ids[tP + pbase + 64 + j];

    f32x4 va[8], vb[8];
#pragma unroll
    for (int pass = 0; pass < 2; ++pass) {
#pragma unroll
        for (int i = 0; i < 4; ++i) {
            const int p = __shfl(posv[pass], i * 4 + q);
            const float* row = xt + (size_t)p * D_ + 8 * j;
            va[pass * 4 + i] = *(const f32x4*)(row);
            vb[pass * 4 + i] = *(const f32x4*)(row + 4);
        }
    }

    float acc[L_];
#pragma unroll
    for (int ll = 0; ll < L_; ++ll) acc[ll] = 0.f;

#pragma unroll
    for (int pass = 0; pass < 2; ++pass) {
#pragma unroll
        for (int i = 0; i < 4; ++i) {
            const f32x4 a = va[pass * 4 + i], c = vb[pass * 4 + i];
            float s  = a.x + a.y + a.z + a.w + c.x + c.y + c.z + c.w;
            float ss = a.x*a.x + a.y*a.y + a.z*a.z + a.w*a.w
                     + c.x*c.x + c.y*c.y + c.z*c.z + c.w*c.w;
            float dot = a.x*g0.x + a.y*g0.y + a.z*g0.z + a.w*g0.w
                      + c.x*g1.x + c.y*g1.y + c.z*g1.z + c.w*g1.w;
#pragma unroll
            for (int m = 1; m < 16; m <<= 1) {
                s  += __shfl_xor(s, m);
                ss += __shfl_xor(ss, m);
            }
            const float mean = s * (1.f / 128.f);
            const float rstd = rsqrtf(ss * (1.f / 128.f) - mean * mean + 1e-5f);
            const float srow = (dot - mean * G) * rstd + B;
            const int l = __shfl(nidv[pass], i * 4 + q) >> 12;
#pragma unroll
            for (int ll = 0; ll < L_; ++ll) acc[ll] += (ll == l) ? srow : 0.f;
        }
    }

#pragma unroll
    for (int ll = 0; ll < L_; ++ll) {
        acc[ll] += __shfl_xor(acc[ll], 16);
        acc[ll] += __shfl_xor(acc[ll], 32);
    }
    if (lane < 16) {
#pragma unroll
        for (int ll = 0; ll < L_; ++ll) lds[wid * 128 + ll * 16 + j] = acc[ll];
    }
    __syncthreads();
    if (tid < 128) {
        const float sum = lds[tid] + lds[128 + tid] + lds[256 + tid] + lds[384 + tid];
        partial[(size_t)b * 128 + tid] = sum;   // deterministic overwrite
    }
}

// ---------------------------------------------------------------------------
// Kernel 3 (fused finalize + broadcast):
// Each block redundantly finalizes its t (reads 64 partial chunks = 32 KB,
// L2-hot; no sync primitives — kernel boundary gives visibility; identical
// inputs -> bit-identical dec[] in every block). Then streams its 1 MB
// slice wave-contiguously with nt f32x4 stores.
// This round: 256 blocks (1/CU, fill-like long-lived blocks; was 512).
// Block b: t = b>>4, s = b&15 -> rows [s*2048,(s+1)*2048), one l = s>>1.
// ---------------------------------------------------------------------------
__global__ __launch_bounds__(256) void k3_finalize_broadcast(
    const float* __restrict__ partial,
    const float* __restrict__ g_fin, const float* __restrict__ b_fin,
    const float* __restrict__ g_dec, const float* __restrict__ b_dec,
    f32x4* __restrict__ out)
{
    __shared__ float hsum[2][128];
    __shared__ float dec[128];
    const int tid  = threadIdx.x;
    const int lane = tid & 63;
    const int wid  = tid >> 6;
    const int b    = blockIdx.x;
    const int t    = b >> 4;
    const int s    = b & 15;                     // 2048-row slice, one l = s>>1

    // ---- per-block finalize (R11-proven) -----------------------------------
    {
        const float* pb = partial + (size_t)t * BLOCKS_PER_T * 128;
        const int ch = tid & 127, h = tid >> 7;  // h in {0,1}: 32 chunks each
        float a = 0.f;
#pragma unroll 8
        for (int k = 0; k < 32; ++k)
            a += pb[(h * 32 + k) * 128 + ch];
        hsum[h][ch] = a;
        __syncthreads();
        if (wid == 0) {
            float c0 = (hsum[0][lane] + hsum[1][lane]) * (1.f / 32768.f);
            float c1 = (hsum[0][64 + lane] + hsum[1][64 + lane]) * (1.f / 32768.f);
            float sm = c0 + c1, ss = c0 * c0 + c1 * c1;
#pragma unroll
            for (int m = 1; m < 64; m <<= 1) {
                sm += __shfl_xor(sm, m);
                ss += __shfl_xor(ss, m);
            }
            const float mean = sm * (1.f / 128.f);
            const float rstd = rsqrtf(ss * (1.f / 128.f) - mean * mean + 1e-5f);
            const float e0 = (c0 - mean) * rstd * g_fin[lane]      + b_fin[lane];
            const float e1 = (c1 - mean) * rstd * g_fin[lane + 64] + b_fin[lane + 64];

            float s0 = e0, q0 = e0 * e0, s1 = e1, q1 = e1 * e1;
#pragma unroll
            for (int m = 1; m < 16; m <<= 1) {
                s0 += __shfl_xor(s0, m); q0 += __shfl_xor(q0, m);
                s1 += __shfl_xor(s1, m); q1 += __shfl_xor(q1, m);
            }
            const float m0 = s0 * (1.f / 16.f), m1 = s1 * (1.f / 16.f);
            const float r0 = rsqrtf(q0 * (1.f / 16.f) - m0 * m0 + 1e-5f);
            const float r1 = rsqrtf(q1 * (1.f / 16.f) - m1 * m1 + 1e-5f);
            const int c = lane & 15;
            const float gd = g_dec[c], bd = b_dec[c];
            dec[lane]      = (e0 - m0) * r0 * gd + bd;
            dec[64 + lane] = (e1 - m1) * r1 * gd + bd;
        }
        __syncthreads();
    }

    // ---- stream 1 MB slice (wave-contiguous, nt) ---------------------------
    const int l = s >> 1;
    const float val = dec[(l << 4) + ((lane & 31) >> 1)];
    const f32x4 v4 = {val, val, val, val};
    // block slice: 65536 f32x4; wave chunk: 16384 f32x4 = 256 KB contiguous
    f32x4* p = out + (((size_t)t << 20) + ((size_t)s << 16) + (wid << 14) + lane);
#pragma unroll 8
    for (int it = 0; it < 256; ++it)
        __builtin_nontemporal_store(v4, p + (it << 6));
}

extern "C" void kernel_launch(void* const* d_in, const int* in_sizes, int n_in,
                              void* d_out, int out_size, void* d_ws, size_t ws_size,
                              hipStream_t stream)
{
    const float* x      = (const float*)d_in[0];
    const float* g_enc  = (const float*)d_in[1];
    const float* b_enc  = (const float*)d_in[2];
    const float* g_fin  = (const float*)d_in[3];
    const float* b_fin  = (const float*)d_in[4];
    const float* g_dec  = (const float*)d_in[5];
    const float* b_dec  = (const float*)d_in[6];
    const int*   node_pos = (const int*)d_in[7];
    const int*   node_ids = (const int*)d_in[8];

    float* partial = (float*)d_ws;      // 1024*128 f32 = 512 KB
    float* out     = (float*)d_out;

    hipLaunchKernelGGL(k1_gather_ln_pool, dim3(K1_BLOCKS), dim3(256), 0, stream,
                       x, g_enc, b_enc, node_pos, node_ids, partial);
    hipLaunchKernelGGL(k3_finalize_broadcast, dim3(K3_BLOCKS), dim3(256), 0, stream,
                       partial, g_fin, b_fin, g_dec, b_dec, (f32x4*)out);
}

// Round 13
// 68.593 us; speedup vs baseline: 1.0805x; 1.0805x over previous
//
#include <hip/hip_runtime.h>

// Problem constants (fixed by setup_inputs)
#define T_   16
#define TOK_ 16384
#define P_   8192
#define N_   32768
#define D_   128
#define L_   8
#define C_   16

typedef float f32x4 __attribute__((ext_vector_type(4)));

constexpr int K1_BLOCKS     = 1024;  // 4/CU
constexpr int BLOCKS_PER_T  = 64;    // K1 blocks per timestamp
constexpr int K3_BLOCKS     = 512;   // 2/CU — measured optimum (2048:-1.4, 256:-5.6)

// ---------------------------------------------------------------------------
// Kernel 1: gather x rows at node_pos, LN(D=128) with algebraically-fused
// 8->1 pool, per-group-l accumulate -> partial[b][128].  (R11-proven)
// All 16 gather f32x4 loads + both passes' index loads issue up-front ->
// one memory round-trip per wave.
// ---------------------------------------------------------------------------
__global__ __launch_bounds__(256) void k1_gather_ln_pool(
    const float* __restrict__ x,
    const float* __restrict__ g_enc, const float* __restrict__ b_enc,
    const int* __restrict__ node_pos, const int* __restrict__ node_ids,
    float* __restrict__ partial)
{
    __shared__ float lds[4 * 128];
    const int tid   = threadIdx.x;
    const int lane  = tid & 63;
    const int wid   = tid >> 6;
    const int j     = lane & 15;   // channel sublane
    const int q     = lane >> 4;   // quarter (row within 4-row batch)
    const int b     = blockIdx.x;
    const int t     = b >> 6;      // 64 blocks per t
    const int chunk = b & 63;
    const int tP    = t * P_;
    const int pbase = chunk * 128 + wid * 16;   // pass 0 rows; pass 1 = +64
    const float* xt = x + (size_t)t * TOK_ * D_;

    const f32x4 g0  = *(const f32x4*)(g_enc + 8 * j);
    const f32x4 g1  = *(const f32x4*)(g_enc + 8 * j + 4);
    const f32x4 bb0 = *(const f32x4*)(b_enc + 8 * j);
    const f32x4 bb1 = *(const f32x4*)(b_enc + 8 * j + 4);
    const float G = g0.x + g0.y + g0.z + g0.w + g1.x + g1.y + g1.z + g1.w;
    const float B = bb0.x + bb0.y + bb0.z + bb0.w + bb1.x + bb1.y + bb1.z + bb1.w;

    int posv[2], nidv[2];
    posv[0] = node_pos[tP + pbase + j];
    nidv[0] = node_ids[tP + pbase + j];
    posv[1] = node_pos[tP + pbase + 64 + j];
    nidv[1] = node_ids[tP + pbase + 64 + j];

    f32x4 va[8], vb[8];
#pragma unroll
    for (int pass = 0; pass < 2; ++pass) {
#pragma unroll
        for (int i = 0; i < 4; ++i) {
            const int p = __shfl(posv[pass], i * 4 + q);
            const float* row = xt + (size_t)p * D_ + 8 * j;
            va[pass * 4 + i] = *(const f32x4*)(row);
            vb[pass * 4 + i] = *(const f32x4*)(row + 4);
        }
    }

    float acc[L_];
#pragma unroll
    for (int ll = 0; ll < L_; ++ll) acc[ll] = 0.f;

#pragma unroll
    for (int pass = 0; pass < 2; ++pass) {
#pragma unroll
        for (int i = 0; i < 4; ++i) {
            const f32x4 a = va[pass * 4 + i], c = vb[pass * 4 + i];
            float s  = a.x + a.y + a.z + a.w + c.x + c.y + c.z + c.w;
            float ss = a.x*a.x + a.y*a.y + a.z*a.z + a.w*a.w
                     + c.x*c.x + c.y*c.y + c.z*c.z + c.w*c.w;
            float dot = a.x*g0.x + a.y*g0.y + a.z*g0.z + a.w*g0.w
                      + c.x*g1.x + c.y*g1.y + c.z*g1.z + c.w*g1.w;
#pragma unroll
            for (int m = 1; m < 16; m <<= 1) {
                s  += __shfl_xor(s, m);
                ss += __shfl_xor(ss, m);
            }
            const float mean = s * (1.f / 128.f);
            const float rstd = rsqrtf(ss * (1.f / 128.f) - mean * mean + 1e-5f);
            const float srow = (dot - mean * G) * rstd + B;
            const int l = __shfl(nidv[pass], i * 4 + q) >> 12;
#pragma unroll
            for (int ll = 0; ll < L_; ++ll) acc[ll] += (ll == l) ? srow : 0.f;
        }
    }

#pragma unroll
    for (int ll = 0; ll < L_; ++ll) {
        acc[ll] += __shfl_xor(acc[ll], 16);
        acc[ll] += __shfl_xor(acc[ll], 32);
    }
    if (lane < 16) {
#pragma unroll
        for (int ll = 0; ll < L_; ++ll) lds[wid * 128 + ll * 16 + j] = acc[ll];
    }
    __syncthreads();
    if (tid < 128) {
        const float sum = lds[tid] + lds[128 + tid] + lds[256 + tid] + lds[384 + tid];
        partial[(size_t)b * 128 + tid] = sum;   // deterministic overwrite
    }
}

// ---------------------------------------------------------------------------
// Kernel 3 (fused finalize + broadcast), R11-proven:
// Each block redundantly finalizes its t (reads 64 partial chunks = 32 KB,
// L2-hot; no sync primitives — kernel boundary gives visibility; identical
// inputs -> bit-identical dec[] in every block). Then streams its 512 KB
// slice wave-contiguously with nt f32x4 stores.
// Block b: t = b>>5, s = b&31 -> rows [s*1024,(s+1)*1024), one l = s>>2.
// ---------------------------------------------------------------------------
__global__ __launch_bounds__(256) void k3_finalize_broadcast(
    const float* __restrict__ partial,
    const float* __restrict__ g_fin, const float* __restrict__ b_fin,
    const float* __restrict__ g_dec, const float* __restrict__ b_dec,
    f32x4* __restrict__ out)
{
    __shared__ float hsum[2][128];
    __shared__ float dec[128];
    const int tid  = threadIdx.x;
    const int lane = tid & 63;
    const int wid  = tid >> 6;
    const int b    = blockIdx.x;
    const int t    = b >> 5;
    const int s    = b & 31;                     // 1024-row slice, one l = s>>2

    // ---- per-block finalize ------------------------------------------------
    {
        const float* pb = partial + (size_t)t * BLOCKS_PER_T * 128;
        const int ch = tid & 127, h = tid >> 7;  // h in {0,1}: 32 chunks each
        float a = 0.f;
#pragma unroll 8
        for (int k = 0; k < 32; ++k)
            a += pb[(h * 32 + k) * 128 + ch];
        hsum[h][ch] = a;
        __syncthreads();
        if (wid == 0) {
            float c0 = (hsum[0][lane] + hsum[1][lane]) * (1.f / 32768.f);
            float c1 = (hsum[0][64 + lane] + hsum[1][64 + lane]) * (1.f / 32768.f);
            float sm = c0 + c1, ss = c0 * c0 + c1 * c1;
#pragma unroll
            for (int m = 1; m < 64; m <<= 1) {
                sm += __shfl_xor(sm, m);
                ss += __shfl_xor(ss, m);
            }
            const float mean = sm * (1.f / 128.f);
            const float rstd = rsqrtf(ss * (1.f / 128.f) - mean * mean + 1e-5f);
            const float e0 = (c0 - mean) * rstd * g_fin[lane]      + b_fin[lane];
            const float e1 = (c1 - mean) * rstd * g_fin[lane + 64] + b_fin[lane + 64];

            float s0 = e0, q0 = e0 * e0, s1 = e1, q1 = e1 * e1;
#pragma unroll
            for (int m = 1; m < 16; m <<= 1) {
                s0 += __shfl_xor(s0, m); q0 += __shfl_xor(q0, m);
                s1 += __shfl_xor(s1, m); q1 += __shfl_xor(q1, m);
            }
            const float m0 = s0 * (1.f / 16.f), m1 = s1 * (1.f / 16.f);
            const float r0 = rsqrtf(q0 * (1.f / 16.f) - m0 * m0 + 1e-5f);
            const float r1 = rsqrtf(q1 * (1.f / 16.f) - m1 * m1 + 1e-5f);
            const int c = lane & 15;
            const float gd = g_dec[c], bd = b_dec[c];
            dec[lane]      = (e0 - m0) * r0 * gd + bd;
            dec[64 + lane] = (e1 - m1) * r1 * gd + bd;
        }
        __syncthreads();
    }

    // ---- stream 512 KB slice (wave-contiguous, nt) -------------------------
    const int l = s >> 2;
    const float val = dec[(l << 4) + ((lane & 31) >> 1)];
    const f32x4 v4 = {val, val, val, val};
    f32x4* p = out + (((size_t)t << 20) + ((size_t)s << 15) + (wid << 13) + lane);
#pragma unroll 8
    for (int it = 0; it < 128; ++it)
        __builtin_nontemporal_store(v4, p + (it << 6));
}

extern "C" void kernel_launch(void* const* d_in, const int* in_sizes, int n_in,
                              void* d_out, int out_size, void* d_ws, size_t ws_size,
                              hipStream_t stream)
{
    const float* x      = (const float*)d_in[0];
    const float* g_enc  = (const float*)d_in[1];
    const float* b_enc  = (const float*)d_in[2];
    const float* g_fin  = (const float*)d_in[3];
    const float* b_fin  = (const float*)d_in[4];
    const float* g_dec  = (const float*)d_in[5];
    const float* b_dec  = (const float*)d_in[6];
    const int*   node_pos = (const int*)d_in[7];
    const int*   node_ids = (const int*)d_in[8];

    float* partial = (float*)d_ws;      // 1024*128 f32 = 512 KB
    float* out     = (float*)d_out;

    hipLaunchKernelGGL(k1_gather_ln_pool, dim3(K1_BLOCKS), dim3(256), 0, stream,
                       x, g_enc, b_enc, node_pos, node_ids, partial);
    hipLaunchKernelGGL(k3_finalize_broadcast, dim3(K3_BLOCKS), dim3(256), 0, stream,
                       partial, g_fin, b_fin, g_dec, b_dec, (f32x4*)out);
}